// Round 10
// baseline (234.765 us; speedup 1.0000x reference)
//
#include <hip/hip_runtime.h>
#include <hip/hip_bf16.h>
#include <cstdint>

typedef unsigned short u16;
typedef unsigned int u32;
typedef unsigned long long u64;
typedef __bf16 bf16x8 __attribute__((ext_vector_type(8)));
typedef float f32x4 __attribute__((ext_vector_type(4)));
typedef u16 u16x8 __attribute__((ext_vector_type(8)));

// ---------- helpers ----------
__device__ __forceinline__ u16 f2b(float f) {          // fp32 -> bf16 RNE
    unsigned int u = __float_as_uint(f);
    u += 0x7fffu + ((u >> 16) & 1u);
    return (u16)(u >> 16);
}
__device__ __forceinline__ float b2f(u16 h) {
    return __uint_as_float(((unsigned int)h) << 16);
}
__device__ __forceinline__ void async_cp16(void* lds, const void* g) {
    __builtin_amdgcn_global_load_lds((const __attribute__((address_space(1))) void*)g,
                                     (__attribute__((address_space(3))) void*)lds, 16, 0, 0);
}
// monotone unsigned mapping of float bits (order-preserving, EXACT)
__device__ __forceinline__ u32 fmono(float f) {
    u32 u = __float_as_uint(f);
    return u ^ (((u32)((int)u >> 31)) | 0x80000000u);
}
__device__ __forceinline__ u64 shfl_xor_u64(u64 v, int mask) {
    u32 lo = (u32)v, hi = (u32)(v >> 32);
    lo = (u32)__shfl_xor((int)lo, mask);
    hi = (u32)__shfl_xor((int)hi, mask);
    return ((u64)hi << 32) | lo;
}
// insert exact key into descending top-3 (keys unique: idx field breaks ties)
__device__ __forceinline__ void ins3(u64 k, u64& k0, u64& k1, u64& k2) {
    bool c0 = k > k0, c1 = k > k1, c2 = k > k2;
    k2 = c1 ? k1 : (c2 ? k : k2);
    k1 = c0 ? k0 : (c1 ? k : k1);
    k0 = c0 ? k : k0;
}
// padded pk index: one float4 pad every 64 entries (chunk groups on distinct banks)
__device__ __forceinline__ int pkix(int i) { return i + (i >> 6); }

// ================= prep kernel: three_nn FIRST, then cvt + transposes =================
#define NB_NN  512
#define NB_CVT 160
#define NB_T2  512
#define NB_T1  1024

__global__ __launch_bounds__(256, 4) void prep_kernel(const float* __restrict__ w1,
                                                      const float* __restrict__ w2,
                                                      u16* __restrict__ wb,
                                                      const float* __restrict__ feature2,
                                                      u16* __restrict__ f2t,
                                                      const float* __restrict__ feature1,
                                                      u16* __restrict__ f1t,
                                                      const float* __restrict__ pos1,
                                                      const float* __restrict__ pos2,
                                                      int* __restrict__ idx_out,
                                                      float* __restrict__ w_out) {
    __shared__ __align__(16) char smem[22784];   // 16640 pk-half + 6144 warr
    int bi = blockIdx.x;
    int tid = threadIdx.x;

    if (bi >= NB_NN) {
        int ci = bi - NB_NN;
        if (ci < NB_CVT) {
            int i = ci * 256 + tid;
            if (i < 40960) {
                const float* src = (i < 24576) ? w1 : w2;
                int k = (i < 24576) ? i : (i - 24576);
                float4 v = *(const float4*)&src[(size_t)k * 4];
                ushort4 o;
                o.x = f2b(v.x); o.y = f2b(v.y); o.z = f2b(v.z); o.w = f2b(v.w);
                *(ushort4*)&wb[(size_t)i * 4] = o;
            }
            return;
        }
        // ---- transpose [B][C][S] -> [B][S][C] bf16 ----
        float (*t)[65] = (float (*)[65])smem;
        const float* in; u16* out; int C, S, s0, c0, b;
        if (ci < NB_CVT + NB_T2) {
            int lin = ci - NB_CVT;
            C = 256; S = 2048; in = feature2; out = f2t;
            s0 = (lin & 31) * 64; c0 = ((lin >> 5) & 3) * 64; b = lin >> 7;
        } else {
            int lin = ci - NB_CVT - NB_T2;
            C = 128; S = 8192; in = feature1; out = f1t;
            s0 = (lin & 127) * 64; c0 = ((lin >> 7) & 1) * 64; b = lin >> 8;
        }
        const float* ib = in + (size_t)b * C * S;
        u16* ob = out + (size_t)b * S * C;
        int col = tid & 63, r0 = tid >> 6;
#pragma unroll
        for (int p = 0; p < 16; ++p) {
            int c = p * 4 + r0;
            t[c][col] = ib[(size_t)(c0 + c) * S + s0 + col];
        }
        __syncthreads();
#pragma unroll
        for (int p = 0; p < 16; ++p) {
            int s = p * 4 + r0;
            ob[(size_t)(s0 + s) * C + c0 + col] = f2b(t[col][s]);
        }
        return;
    }

    // ---- three_nn: 64 queries/block; thread handles queries p, p+16, p+32, p+48 ----
    float4* pk = (float4*)smem;                          // padded: 1040 float4 = 16640 B
    u64* warr = (u64*)(smem + 16640);                    // [4 waves][16 p][4 q][3]
    int j0 = bi * 64;
    int b = j0 >> 13;
    const float* p2 = pos2 + (size_t)b * 3 * 2048;
    int p = tid & 15, ck = tid >> 4;
    int wv = tid >> 6, lane = tid & 63;
    const float* p1 = pos1 + (size_t)b * 3 * 8192;
    float qx[4], qy[4], qz[4];
#pragma unroll
    for (int t = 0; t < 4; ++t) {
        int n = (j0 & 8191) + p + t * 16;
        qx[t] = p1[n]; qy[t] = p1[8192 + n]; qz[t] = p1[16384 + n];
    }
    u64 key[4][3];
#pragma unroll
    for (int t = 0; t < 4; ++t) { key[t][0] = 0; key[t][1] = 0; key[t][2] = 0; }

    for (int half = 0; half < 2; ++half) {
        int hbase = half * 1024;
        for (int i = tid; i < 1024; i += 256) {
            int s = hbase + i;
            float x = p2[s], y = p2[2048 + s], z = p2[4096 + s];
            pk[pkix(i)] = make_float4(x, y, z, -0.5f * (x * x + y * y + z * z));
        }
        __syncthreads();

        float g[4][3]; int id[4][3];
#pragma unroll
        for (int t = 0; t < 4; ++t) {
            g[t][0] = -3.4e38f; g[t][1] = -3.4e38f; g[t][2] = -3.4e38f;
            id[t][0] = 0; id[t][1] = 0; id[t][2] = 0;
        }
        int sb = ck * 64;
        const float4* pc = pk + pkix(sb);
#pragma unroll 2
        for (int it = 0; it < 64; ++it) {
            float4 cd = pc[it];
            int s = sb + it;
#pragma unroll
            for (int t = 0; t < 4; ++t) {
                float tv = fmaf(qx[t], cd.x, fmaf(qy[t], cd.y, fmaf(qz[t], cd.z, cd.w)));
                bool c0 = tv > g[t][0], c1 = tv > g[t][1], c2 = tv > g[t][2];
                g[t][2] = c1 ? g[t][1] : (c2 ? tv : g[t][2]);
                id[t][2] = c1 ? id[t][1] : (c2 ? s : id[t][2]);
                g[t][1] = c0 ? g[t][0] : (c1 ? tv : g[t][1]);
                id[t][1] = c0 ? id[t][0] : (c1 ? s : id[t][1]);
                g[t][0] = c0 ? tv : g[t][0];
                id[t][0] = c0 ? s : id[t][0];
            }
        }
        __syncthreads();   // reads done before next half restages

#pragma unroll
        for (int t = 0; t < 4; ++t) {
#pragma unroll
            for (int r = 0; r < 3; ++r)
                ins3(((u64)fmono(g[t][r]) << 32) | (u64)(2047 - (hbase + id[t][r])),
                     key[t][0], key[t][1], key[t][2]);
        }
    }

    // in-wave merge across the 4 chunk-groups (lane>>4)
#pragma unroll
    for (int mask = 16; mask <= 32; mask <<= 1) {
#pragma unroll
        for (int t = 0; t < 4; ++t) {
            u64 m0 = shfl_xor_u64(key[t][0], mask);
            u64 m1 = shfl_xor_u64(key[t][1], mask);
            u64 m2 = shfl_xor_u64(key[t][2], mask);
            ins3(m0, key[t][0], key[t][1], key[t][2]);
            ins3(m1, key[t][0], key[t][1], key[t][2]);
            ins3(m2, key[t][0], key[t][1], key[t][2]);
        }
    }
    if (lane < 16) {
        u64* wr = &warr[(wv * 16 + p) * 12];
#pragma unroll
        for (int t = 0; t < 4; ++t) {
            wr[t * 3 + 0] = key[t][0]; wr[t * 3 + 1] = key[t][1]; wr[t * 3 + 2] = key[t][2];
        }
    }
    __syncthreads();
    if (tid < 64) {
        int pp = tid & 15, t = tid >> 4;
        const u64* w0 = &warr[pp * 12 + t * 3];
        u64 k0 = w0[0], k1 = w0[1], k2 = w0[2];
#pragma unroll
        for (int w = 1; w < 4; ++w) {
            const u64* wr = &warr[(w * 16 + pp) * 12 + t * 3];
            ins3(wr[0], k0, k1, k2);
            ins3(wr[1], k0, k1, k2);
            ins3(wr[2], k0, k1, k2);
        }
        int s0 = 2047 - (int)(k0 & 0xFFFFFFFFu);
        int s1 = 2047 - (int)(k1 & 0xFFFFFFFFu);
        int s2 = 2047 - (int)(k2 & 0xFFFFFFFFu);
        int j = j0 + pp + t * 16;
        int n = j & 8191;
        float x1 = p1[n], y1 = p1[8192 + n], z1 = p1[16384 + n];
        float n1 = x1 * x1 + y1 * y1 + z1 * z1;
        float X0 = p2[s0], Y0 = p2[2048 + s0], Z0 = p2[4096 + s0];
        float X1 = p2[s1], Y1v = p2[2048 + s1], Z1 = p2[4096 + s1];
        float X2 = p2[s2], Y2v = p2[2048 + s2], Z2 = p2[4096 + s2];
        float t0 = x1 * X0 + y1 * Y0 + z1 * Z0 - 0.5f * (X0 * X0 + Y0 * Y0 + Z0 * Z0);
        float t1 = x1 * X1 + y1 * Y1v + z1 * Z1 - 0.5f * (X1 * X1 + Y1v * Y1v + Z1 * Z1);
        float t2 = x1 * X2 + y1 * Y2v + z1 * Z2 - 0.5f * (X2 * X2 + Y2v * Y2v + Z2 * Z2);
        float d0 = fmaxf(fmaf(-2.f, t0, n1), 1e-10f);
        float d1 = fmaxf(fmaf(-2.f, t1, n1), 1e-10f);
        float d2 = fmaxf(fmaf(-2.f, t2, n1), 1e-10f);
        float w0v = 1.f / d0, w1v = 1.f / d1, w2v = 1.f / d2;
        float inv = 1.f / (w0v + w1v + w2v);
        idx_out[j * 3] = s0; idx_out[j * 3 + 1] = s1; idx_out[j * 3 + 2] = s2;
        w_out[j * 3] = w0v * inv; w_out[j * 3 + 1] = w1v * inv; w_out[j * 3 + 2] = w2v * inv;
    }
}

// ---------- GEMM: Yb[j][m] = bf16(sum_k A[j][k]*Bw[m][k] + bias[m]), fused BN stats ----------
// 64(j) x 128(m) tile, grid 512x2 = 1024 blocks (4/CU). Wave: 32x64 via 2x4 MFMA 16x16x32.
// GATHER: k<256 A built on the fly = interp gather from F2T (idx/wgt in regs);
//         k>=256 A from F1T (stride 128) via async copy.
// FUSE:   A = relu(bn1(Y1)) in-register during staging (BN table in LDS).
// Epilogue: LDS bounce (stride 136) -> coalesced u16x8 stores.
template <int KT, bool GATHER, bool FUSE>
__global__ __launch_bounds__(256, 4) void gemm_kernel(const u16* __restrict__ A1,
                                                      const u16* __restrict__ A2,
                                                      const u16* __restrict__ Bw,
                                                      const float* __restrict__ bias,
                                                      const int* __restrict__ idx,
                                                      const float* __restrict__ wgt,
                                                      const float* __restrict__ stats_in,
                                                      const float* __restrict__ g_in,
                                                      const float* __restrict__ be_in,
                                                      u16* __restrict__ Yb,
                                                      float* __restrict__ stats) {
    __shared__ __align__(16) char smemA[26624];
    u16* Al = (u16*)smemA;                       // [64][64] = 8 KB, k-loop
    u16* Bl = (u16*)(smemA + 8192);              // [128][64] = 16 KB, k-loop
    u16* T  = (u16*)smemA;                       // [64][136] = 17408 B epilogue bounce
    float2* BNT = (float2*)(smemA + 24576);      // 256 x (scale, shift), FUSE only
    int tid = threadIdx.x;
    int lane = tid & 63, wv = tid >> 6;
    int j0 = blockIdx.x * 64, m0 = blockIdx.y * 128;
    int l15 = lane & 15, q = lane >> 4;
    int wj = (wv >> 1) * 32, wm = (wv & 1) * 64;
    f32x4 acc[2][4];
#pragma unroll
    for (int i = 0; i < 2; ++i)
#pragma unroll
        for (int jj = 0; jj < 4; ++jj) acc[i][jj] = (f32x4){0.f, 0.f, 0.f, 0.f};

    int lrow = lane >> 3, lchunk = lane & 7;
    const u16* Bg = Bw + (size_t)m0 * KT;

    if (FUSE) {
        int m = tid;
        const float inv = 1.f / 32768.f;
        float mean = stats_in[m] * inv;
        float var = stats_in[256 + m] * inv - mean * mean;
        float a = g_in[m] * rsqrtf(var + 1e-5f);
        BNT[m] = make_float2(a, be_in[m] - mean * a);
        __syncthreads();
    }

    // GATHER: hoist this thread's 2 rows' idx/wgt + row base pointers into registers
    const u16* grow0[2]; const u16* grow1[2]; const u16* grow2[2];
    float gw0[2], gw1[2], gw2[2];
    if (GATHER) {
#pragma unroll
        for (int qq = 0; qq < 2; ++qq) {
            int jl = wv * 8 + qq * 32 + lrow;
            int j = j0 + jl;
            int bb = j >> 13;
            const u16* fb = A1 + (size_t)bb * 2048 * 256;   // A1 = F2T
            grow0[qq] = fb + (size_t)idx[j * 3 + 0] * 256;
            grow1[qq] = fb + (size_t)idx[j * 3 + 1] * 256;
            grow2[qq] = fb + (size_t)idx[j * 3 + 2] * 256;
            gw0[qq] = wgt[j * 3 + 0]; gw1[qq] = wgt[j * 3 + 1]; gw2[qq] = wgt[j * 3 + 2];
        }
    }

    for (int k0 = 0; k0 < KT; k0 += 64) {
        // B staging first (async DMA overlaps the A VALU work below)
#pragma unroll
        for (int pass = 0; pass < 4; ++pass) {
            int row = wv * 8 + pass * 32;   // wave-uniform; HW adds lane*16B (8 rows/wave)
            async_cp16(&Bl[row * 64], Bg + (size_t)(row + lrow) * KT + k0 + lchunk * 8);
        }
        if (GATHER && k0 < 256) {
            int c = k0 + lchunk * 8;
#pragma unroll
            for (int qq = 0; qq < 2; ++qq) {
                int row = wv * 8 + qq * 32 + lrow;
                u16x8 v0 = *(const u16x8*)(grow0[qq] + c);
                u16x8 v1 = *(const u16x8*)(grow1[qq] + c);
                u16x8 v2 = *(const u16x8*)(grow2[qq] + c);
                u16x8 o;
#pragma unroll
                for (int e = 0; e < 8; ++e)
                    o[e] = f2b(gw0[qq] * b2f(v0[e]) + gw1[qq] * b2f(v1[e]) + gw2[qq] * b2f(v2[e]));
                *(u16x8*)&Al[row * 64 + lchunk * 8] = o;
            }
        } else if (FUSE) {
            int c = k0 + lchunk * 8;
            float2 bn[8];
#pragma unroll
            for (int e = 0; e < 8; ++e) bn[e] = BNT[c + e];
#pragma unroll
            for (int qq = 0; qq < 2; ++qq) {
                int row = wv * 8 + qq * 32 + lrow;
                u16x8 y = *(const u16x8*)&A1[(size_t)(j0 + row) * 256 + c];
                u16x8 o;
#pragma unroll
                for (int e = 0; e < 8; ++e)
                    o[e] = f2b(fmaxf(b2f(y[e]) * bn[e].x + bn[e].y, 0.f));
                *(u16x8*)&Al[row * 64 + lchunk * 8] = o;
            }
        } else {
            // k >= 256 region of GATHER gemm: A from F1T, stride 128
            const u16* src = A2 + (size_t)j0 * 128 + (k0 - 256);
#pragma unroll
            for (int pass = 0; pass < 2; ++pass) {
                int row = wv * 8 + pass * 32;   // wave-uniform LDS base
                async_cp16(&Al[row * 64], src + (size_t)(row + lrow) * 128 + lchunk * 8);
            }
        }
        __syncthreads();
#pragma unroll
        for (int ks = 0; ks < 2; ++ks) {
            bf16x8 af[2], bfr[4];
#pragma unroll
            for (int i = 0; i < 2; ++i)
                af[i] = *(const bf16x8*)&Al[(wj + i * 16 + l15) * 64 + ks * 32 + q * 8];
#pragma unroll
            for (int jj = 0; jj < 4; ++jj)
                bfr[jj] = *(const bf16x8*)&Bl[(wm + jj * 16 + l15) * 64 + ks * 32 + q * 8];
#pragma unroll
            for (int i = 0; i < 2; ++i)
#pragma unroll
                for (int jj = 0; jj < 4; ++jj)
                    acc[i][jj] = __builtin_amdgcn_mfma_f32_16x16x32_bf16(af[i], bfr[jj],
                                                                         acc[i][jj], 0, 0, 0);
        }
        __syncthreads();
    }
    // epilogue: stats + bf16 tile into LDS (D col = lane&15 -> m, row = q*4+reg -> j)
#pragma unroll
    for (int jj = 0; jj < 4; ++jj) {
        int ml = wm + jj * 16 + l15;
        float bv = bias[m0 + ml];
        float s = 0.f, s2 = 0.f;
#pragma unroll
        for (int i = 0; i < 2; ++i) {
            int jl = wj + i * 16 + q * 4;
#pragma unroll
            for (int r = 0; r < 4; ++r) {
                float v = acc[i][jj][r] + bv;
                s += v; s2 += v * v;
                T[(jl + r) * 136 + ml] = f2b(v);
            }
        }
        s += __shfl_xor(s, 16); s += __shfl_xor(s, 32);
        s2 += __shfl_xor(s2, 16); s2 += __shfl_xor(s2, 32);
        if (q == 0) {
            atomicAdd(&stats[m0 + ml], s);
            atomicAdd(&stats[256 + m0 + ml], s2);
        }
    }
    __syncthreads();
    // coalesced store: 16 rows x 128 ch per iter (256 B segments)
#pragma unroll
    for (int it = 0; it < 4; ++it) {
        int jl = it * 16 + wv * 4 + q;
        u16x8 v = *(const u16x8*)&T[jl * 136 + l15 * 8];
        *(u16x8*)&Yb[(size_t)(j0 + jl) * 256 + m0 + l15 * 8] = v;
    }
}

// ---------- BN2+ReLU (inline finalize) + transpose [j][o] -> out[b][o][n] ----------
__global__ __launch_bounds__(256) void final_out_kernel(const u16* __restrict__ Y2,
                                                        const float* __restrict__ stats,
                                                        const float* __restrict__ g,
                                                        const float* __restrict__ be,
                                                        float* __restrict__ out) {
    __shared__ float t[64][65];
    int j0 = blockIdx.x * 64, o0 = blockIdx.y * 64;
    int tid = threadIdx.x;
    int c4 = (tid & 15) * 4, rw = tid >> 4;
#pragma unroll
    for (int p = 0; p < 4; ++p) {
        int jl = p * 16 + rw;
        ushort4 v = *(const ushort4*)&Y2[(size_t)(j0 + jl) * 256 + o0 + c4];
        t[jl][c4] = b2f(v.x); t[jl][c4 + 1] = b2f(v.y);
        t[jl][c4 + 2] = b2f(v.z); t[jl][c4 + 3] = b2f(v.w);
    }
    __syncthreads();
    int b = j0 >> 13, n0 = j0 & 8191;
    const float inv = 1.f / 32768.f;
#pragma unroll
    for (int p = 0; p < 4; ++p) {
        int ol = p * 16 + rw;
        int o = o0 + ol;
        float mean = stats[o] * inv;
        float var = stats[256 + o] * inv - mean * mean;
        float a = g[o] * rsqrtf(var + 1e-5f);
        float s = be[o] - mean * a;
        float4 v;
        v.x = fmaxf(t[c4][ol] * a + s, 0.f);
        v.y = fmaxf(t[c4 + 1][ol] * a + s, 0.f);
        v.z = fmaxf(t[c4 + 2][ol] * a + s, 0.f);
        v.w = fmaxf(t[c4 + 3][ol] * a + s, 0.f);
        *(float4*)&out[(size_t)b * 2097152 + (size_t)o * 8192 + n0 + c4] = v;
    }
}

extern "C" void kernel_launch(void* const* d_in, const int* in_sizes, int n_in,
                              void* d_out, int out_size, void* d_ws, size_t ws_size,
                              hipStream_t stream) {
    const float* pos1 = (const float*)d_in[0];
    const float* pos2 = (const float*)d_in[1];
    const float* feature1 = (const float*)d_in[2];
    const float* feature2 = (const float*)d_in[3];
    const float* W1 = (const float*)d_in[4];
    const float* b1 = (const float*)d_in[5];
    const float* g1 = (const float*)d_in[6];
    const float* be1 = (const float*)d_in[7];
    const float* W2 = (const float*)d_in[8];
    const float* b2 = (const float*)d_in[9];
    const float* g2 = (const float*)d_in[10];
    const float* be2 = (const float*)d_in[11];

    char* ws = (char*)d_ws;
    int*   IDX    = (int*)(ws + 0);                 // 393216 B
    float* WGT    = (float*)(ws + 393216);          // 393216 B
    u16*   W1B    = (u16*)(ws + 786432);            // 196608 B
    u16*   W2B    = (u16*)(ws + 983040);            // 131072 B (contiguous after W1B)
    float* STATS  = (float*)(ws + 1114112);         // 4096 B: sum1/sq1/sum2/sq2
    u16*   F2T    = (u16*)(ws + 1118208);           // 4 MiB  [4][2048][256]
    u16*   F1T    = (u16*)(ws + 5312512);           // 8 MiB  [4][8192][128]
    u16*   Y1     = (u16*)(ws + 13701120);          // 16 MiB [32768][256]
    u16*   Y2     = (u16*)(ws + 30478336);          // 16 MiB
    float* OUT    = (float*)d_out;

    hipMemsetAsync(STATS, 0, 1024 * sizeof(float), stream);
    prep_kernel<<<NB_NN + NB_CVT + NB_T2 + NB_T1, 256, 0, stream>>>(
        W1, W2, W1B, feature2, F2T, feature1, F1T, pos1, pos2, IDX, WGT);
    gemm_kernel<384, true, false><<<dim3(512, 2), 256, 0, stream>>>(
        F2T, F1T, W1B, b1, IDX, WGT, nullptr, nullptr, nullptr, Y1, STATS);
    gemm_kernel<256, false, true><<<dim3(512, 2), 256, 0, stream>>>(
        Y1, nullptr, W2B, b2, nullptr, nullptr, STATS, g1, be1, Y2, STATS + 512);
    final_out_kernel<<<dim3(512, 4), 256, 0, stream>>>(Y2, STATS + 512, g2, be2, OUT);
}

// Round 11
// 207.677 us; speedup vs baseline: 1.1304x; 1.1304x over previous
//
#include <hip/hip_runtime.h>
#include <hip/hip_bf16.h>
#include <cstdint>

typedef unsigned short u16;
typedef unsigned int u32;
typedef unsigned long long u64;
typedef __bf16 bf16x8 __attribute__((ext_vector_type(8)));
typedef float f32x4 __attribute__((ext_vector_type(4)));
typedef u16 u16x8 __attribute__((ext_vector_type(8)));

// ---------- helpers ----------
__device__ __forceinline__ u16 f2b(float f) {          // fp32 -> bf16 RNE
    unsigned int u = __float_as_uint(f);
    u += 0x7fffu + ((u >> 16) & 1u);
    return (u16)(u >> 16);
}
__device__ __forceinline__ float b2f(u16 h) {
    return __uint_as_float(((unsigned int)h) << 16);
}
__device__ __forceinline__ void async_cp16(void* lds, const void* g) {
    __builtin_amdgcn_global_load_lds((const __attribute__((address_space(1))) void*)g,
                                     (__attribute__((address_space(3))) void*)lds, 16, 0, 0);
}
// monotone unsigned mapping of float bits (order-preserving, EXACT)
__device__ __forceinline__ u32 fmono(float f) {
    u32 u = __float_as_uint(f);
    return u ^ (((u32)((int)u >> 31)) | 0x80000000u);
}
__device__ __forceinline__ u64 shfl_xor_u64(u64 v, int mask) {
    u32 lo = (u32)v, hi = (u32)(v >> 32);
    lo = (u32)__shfl_xor((int)lo, mask);
    hi = (u32)__shfl_xor((int)hi, mask);
    return ((u64)hi << 32) | lo;
}
// insert exact key into descending top-3 (keys unique: idx field breaks ties)
__device__ __forceinline__ void ins3(u64 k, u64& k0, u64& k1, u64& k2) {
    bool c0 = k > k0, c1 = k > k1, c2 = k > k2;
    k2 = c1 ? k1 : (c2 ? k : k2);
    k1 = c0 ? k0 : (c1 ? k : k1);
    k0 = c0 ? k : k0;
}
// padded pk index: one float4 pad every 64 entries (chunk groups on distinct banks)
__device__ __forceinline__ int pkix(int i) { return i + (i >> 6); }

// ================= prep kernel: three_nn FIRST, then cvt + transposes =================
#define NB_NN  512
#define NB_CVT 160
#define NB_T2  512
#define NB_T1  1024

__global__ __launch_bounds__(256, 4) void prep_kernel(const float* __restrict__ w1,
                                                      const float* __restrict__ w2,
                                                      u16* __restrict__ wb,
                                                      const float* __restrict__ feature2,
                                                      u16* __restrict__ f2t,
                                                      const float* __restrict__ feature1,
                                                      u16* __restrict__ f1t,
                                                      const float* __restrict__ pos1,
                                                      const float* __restrict__ pos2,
                                                      int* __restrict__ idx_out,
                                                      float* __restrict__ w_out) {
    __shared__ __align__(16) char smem[22784];   // 16640 pk-half + 6144 warr
    int bi = blockIdx.x;
    int tid = threadIdx.x;

    if (bi >= NB_NN) {
        int ci = bi - NB_NN;
        if (ci < NB_CVT) {
            int i = ci * 256 + tid;
            if (i < 40960) {
                const float* src = (i < 24576) ? w1 : w2;
                int k = (i < 24576) ? i : (i - 24576);
                float4 v = *(const float4*)&src[(size_t)k * 4];
                ushort4 o;
                o.x = f2b(v.x); o.y = f2b(v.y); o.z = f2b(v.z); o.w = f2b(v.w);
                *(ushort4*)&wb[(size_t)i * 4] = o;
            }
            return;
        }
        // ---- transpose [B][C][S] -> [B][S][C] bf16 ----
        float (*t)[65] = (float (*)[65])smem;
        const float* in; u16* out; int C, S, s0, c0, b;
        if (ci < NB_CVT + NB_T2) {
            int lin = ci - NB_CVT;
            C = 256; S = 2048; in = feature2; out = f2t;
            s0 = (lin & 31) * 64; c0 = ((lin >> 5) & 3) * 64; b = lin >> 7;
        } else {
            int lin = ci - NB_CVT - NB_T2;
            C = 128; S = 8192; in = feature1; out = f1t;
            s0 = (lin & 127) * 64; c0 = ((lin >> 7) & 1) * 64; b = lin >> 8;
        }
        const float* ib = in + (size_t)b * C * S;
        u16* ob = out + (size_t)b * S * C;
        int col = tid & 63, r0 = tid >> 6;
#pragma unroll
        for (int p = 0; p < 16; ++p) {
            int c = p * 4 + r0;
            t[c][col] = ib[(size_t)(c0 + c) * S + s0 + col];
        }
        __syncthreads();
#pragma unroll
        for (int p = 0; p < 16; ++p) {
            int s = p * 4 + r0;
            ob[(size_t)(s0 + s) * C + c0 + col] = f2b(t[col][s]);
        }
        return;
    }

    // ---- three_nn: 64 queries/block; thread handles queries p, p+16, p+32, p+48 ----
    float4* pk = (float4*)smem;                          // padded: 1040 float4 = 16640 B
    u64* warr = (u64*)(smem + 16640);                    // [4 waves][16 p][4 q][3]
    int j0 = bi * 64;
    int b = j0 >> 13;
    const float* p2 = pos2 + (size_t)b * 3 * 2048;
    int p = tid & 15, ck = tid >> 4;
    int wv = tid >> 6, lane = tid & 63;
    const float* p1 = pos1 + (size_t)b * 3 * 8192;
    float qx[4], qy[4], qz[4];
#pragma unroll
    for (int t = 0; t < 4; ++t) {
        int n = (j0 & 8191) + p + t * 16;
        qx[t] = p1[n]; qy[t] = p1[8192 + n]; qz[t] = p1[16384 + n];
    }
    u64 key[4][3];
#pragma unroll
    for (int t = 0; t < 4; ++t) { key[t][0] = 0; key[t][1] = 0; key[t][2] = 0; }

    for (int half = 0; half < 2; ++half) {
        int hbase = half * 1024;
        for (int i = tid; i < 1024; i += 256) {
            int s = hbase + i;
            float x = p2[s], y = p2[2048 + s], z = p2[4096 + s];
            pk[pkix(i)] = make_float4(x, y, z, -0.5f * (x * x + y * y + z * z));
        }
        __syncthreads();

        float g[4][3]; int id[4][3];
#pragma unroll
        for (int t = 0; t < 4; ++t) {
            g[t][0] = -3.4e38f; g[t][1] = -3.4e38f; g[t][2] = -3.4e38f;
            id[t][0] = 0; id[t][1] = 0; id[t][2] = 0;
        }
        int sb = ck * 64;
        const float4* pc = pk + pkix(sb);
#pragma unroll 2
        for (int it = 0; it < 64; ++it) {
            float4 cd = pc[it];
            int s = sb + it;
#pragma unroll
            for (int t = 0; t < 4; ++t) {
                float tv = fmaf(qx[t], cd.x, fmaf(qy[t], cd.y, fmaf(qz[t], cd.z, cd.w)));
                bool c0 = tv > g[t][0], c1 = tv > g[t][1], c2 = tv > g[t][2];
                g[t][2] = c1 ? g[t][1] : (c2 ? tv : g[t][2]);
                id[t][2] = c1 ? id[t][1] : (c2 ? s : id[t][2]);
                g[t][1] = c0 ? g[t][0] : (c1 ? tv : g[t][1]);
                id[t][1] = c0 ? id[t][0] : (c1 ? s : id[t][1]);
                g[t][0] = c0 ? tv : g[t][0];
                id[t][0] = c0 ? s : id[t][0];
            }
        }
        __syncthreads();   // reads done before next half restages

#pragma unroll
        for (int t = 0; t < 4; ++t) {
#pragma unroll
            for (int r = 0; r < 3; ++r)
                ins3(((u64)fmono(g[t][r]) << 32) | (u64)(2047 - (hbase + id[t][r])),
                     key[t][0], key[t][1], key[t][2]);
        }
    }

    // in-wave merge across the 4 chunk-groups (lane>>4)
#pragma unroll
    for (int mask = 16; mask <= 32; mask <<= 1) {
#pragma unroll
        for (int t = 0; t < 4; ++t) {
            u64 m0 = shfl_xor_u64(key[t][0], mask);
            u64 m1 = shfl_xor_u64(key[t][1], mask);
            u64 m2 = shfl_xor_u64(key[t][2], mask);
            ins3(m0, key[t][0], key[t][1], key[t][2]);
            ins3(m1, key[t][0], key[t][1], key[t][2]);
            ins3(m2, key[t][0], key[t][1], key[t][2]);
        }
    }
    if (lane < 16) {
        u64* wr = &warr[(wv * 16 + p) * 12];
#pragma unroll
        for (int t = 0; t < 4; ++t) {
            wr[t * 3 + 0] = key[t][0]; wr[t * 3 + 1] = key[t][1]; wr[t * 3 + 2] = key[t][2];
        }
    }
    __syncthreads();
    if (tid < 64) {
        int pp = tid & 15, t = tid >> 4;
        const u64* w0 = &warr[pp * 12 + t * 3];
        u64 k0 = w0[0], k1 = w0[1], k2 = w0[2];
#pragma unroll
        for (int w = 1; w < 4; ++w) {
            const u64* wr = &warr[(w * 16 + pp) * 12 + t * 3];
            ins3(wr[0], k0, k1, k2);
            ins3(wr[1], k0, k1, k2);
            ins3(wr[2], k0, k1, k2);
        }
        int s0 = 2047 - (int)(k0 & 0xFFFFFFFFu);
        int s1 = 2047 - (int)(k1 & 0xFFFFFFFFu);
        int s2 = 2047 - (int)(k2 & 0xFFFFFFFFu);
        int j = j0 + pp + t * 16;
        int n = j & 8191;
        float x1 = p1[n], y1 = p1[8192 + n], z1 = p1[16384 + n];
        float n1 = x1 * x1 + y1 * y1 + z1 * z1;
        float X0 = p2[s0], Y0 = p2[2048 + s0], Z0 = p2[4096 + s0];
        float X1 = p2[s1], Y1v = p2[2048 + s1], Z1 = p2[4096 + s1];
        float X2 = p2[s2], Y2v = p2[2048 + s2], Z2 = p2[4096 + s2];
        float t0 = x1 * X0 + y1 * Y0 + z1 * Z0 - 0.5f * (X0 * X0 + Y0 * Y0 + Z0 * Z0);
        float t1 = x1 * X1 + y1 * Y1v + z1 * Z1 - 0.5f * (X1 * X1 + Y1v * Y1v + Z1 * Z1);
        float t2 = x1 * X2 + y1 * Y2v + z1 * Z2 - 0.5f * (X2 * X2 + Y2v * Y2v + Z2 * Z2);
        float d0 = fmaxf(fmaf(-2.f, t0, n1), 1e-10f);
        float d1 = fmaxf(fmaf(-2.f, t1, n1), 1e-10f);
        float d2 = fmaxf(fmaf(-2.f, t2, n1), 1e-10f);
        float w0v = 1.f / d0, w1v = 1.f / d1, w2v = 1.f / d2;
        float inv = 1.f / (w0v + w1v + w2v);
        idx_out[j * 3] = s0; idx_out[j * 3 + 1] = s1; idx_out[j * 3 + 2] = s2;
        w_out[j * 3] = w0v * inv; w_out[j * 3 + 1] = w1v * inv; w_out[j * 3 + 2] = w2v * inv;
    }
}

// ---------- GEMM: Yb[j][m] = bf16(sum_k A[j][k]*Bw[m][k] + bias[m]), fused BN stats ----------
// 128x128 tile, grid 256x2. Pipelined K-loop: A double-buffered in LDS (ONE barrier/iter),
// B fragments loaded straight from L2 into registers (weights are L2-hot, no LDS round trip).
// GATHER: k<256 A built on the fly = interp gather from F2T (idx/wgt in regs);
//         k>=256 A from F1T (stride 128) via async copy.
// FUSE:   A = relu(bn1(Y1)) in-register during staging (BN table in LDS).
// Epilogue: LDS bounce (stride 136) -> coalesced u16x8 stores.
template <int KT, bool GATHER, bool FUSE>
__global__ __launch_bounds__(256, 2) void gemm_kernel(const u16* __restrict__ A1,
                                                      const u16* __restrict__ A2,
                                                      const u16* __restrict__ Bw,
                                                      const float* __restrict__ bias,
                                                      const int* __restrict__ idx,
                                                      const float* __restrict__ wgt,
                                                      const float* __restrict__ stats_in,
                                                      const float* __restrict__ g_in,
                                                      const float* __restrict__ be_in,
                                                      u16* __restrict__ Yb,
                                                      float* __restrict__ stats) {
    __shared__ __align__(16) char smemA[34816];
    u16* Al = (u16*)smemA;                       // [2][128][64] = 32 KB, k-loop dbuf
    u16* T  = (u16*)smemA;                       // [128][136] = 34816 B epilogue bounce
    float2* BNT = (float2*)(smemA + 32768);      // 256 x (scale, shift), FUSE only
    int tid = threadIdx.x;
    int lane = tid & 63, wv = tid >> 6;
    int j0 = blockIdx.x * 128, m0 = blockIdx.y * 128;
    int l15 = lane & 15, q = lane >> 4;
    int wj = (wv >> 1) * 64, wm = (wv & 1) * 64;
    f32x4 acc[4][4];
#pragma unroll
    for (int i = 0; i < 4; ++i)
#pragma unroll
        for (int jj = 0; jj < 4; ++jj) acc[i][jj] = (f32x4){0.f, 0.f, 0.f, 0.f};

    int rbase = wv * 32;
    int lrow = lane >> 3, lchunk = lane & 7;
    const u16* Bg = Bw + (size_t)m0 * KT;

    if (FUSE) {
        int m = tid;
        const float inv = 1.f / 32768.f;
        float mean = stats_in[m] * inv;
        float var = stats_in[256 + m] * inv - mean * mean;
        float a = g_in[m] * rsqrtf(var + 1e-5f);
        BNT[m] = make_float2(a, be_in[m] - mean * a);
        __syncthreads();   // BNT visible before first stage
    }

    // GATHER: hoist this thread's 4 rows' idx/wgt + row base pointers into registers
    const u16* grow0[4]; const u16* grow1[4]; const u16* grow2[4];
    float gw0[4], gw1[4], gw2[4];
    if (GATHER) {
#pragma unroll
        for (int qq = 0; qq < 4; ++qq) {
            int jl = rbase + qq * 8 + lrow;
            int j = j0 + jl;
            int bb = j >> 13;
            const u16* fb = A1 + (size_t)bb * 2048 * 256;   // A1 = F2T
            grow0[qq] = fb + (size_t)idx[j * 3 + 0] * 256;
            grow1[qq] = fb + (size_t)idx[j * 3 + 1] * 256;
            grow2[qq] = fb + (size_t)idx[j * 3 + 2] * 256;
            gw0[qq] = wgt[j * 3 + 0]; gw1[qq] = wgt[j * 3 + 1]; gw2[qq] = wgt[j * 3 + 2];
        }
    }

    // stage A tile for k-offset k0s into buffer bsel
    auto stageA = [&](int k0s, int bsel) {
        u16* dst = Al + bsel * 8192;
        if (GATHER && k0s < 256) {
            int c = k0s + lchunk * 8;
#pragma unroll
            for (int qq = 0; qq < 4; ++qq) {
                int row = rbase + qq * 8;
                u16x8 v0 = *(const u16x8*)(grow0[qq] + c);
                u16x8 v1 = *(const u16x8*)(grow1[qq] + c);
                u16x8 v2 = *(const u16x8*)(grow2[qq] + c);
                u16x8 o;
#pragma unroll
                for (int e = 0; e < 8; ++e)
                    o[e] = f2b(gw0[qq] * b2f(v0[e]) + gw1[qq] * b2f(v1[e]) + gw2[qq] * b2f(v2[e]));
                *(u16x8*)&dst[(row + lrow) * 64 + lchunk * 8] = o;
            }
        } else if (FUSE) {
            int c = k0s + lchunk * 8;
            float2 bn[8];
#pragma unroll
            for (int e = 0; e < 8; ++e) bn[e] = BNT[c + e];
#pragma unroll
            for (int qq = 0; qq < 4; ++qq) {
                int row = rbase + qq * 8;
                u16x8 y = *(const u16x8*)&A1[(size_t)(j0 + row + lrow) * 256 + c];
                u16x8 o;
#pragma unroll
                for (int e = 0; e < 8; ++e)
                    o[e] = f2b(fmaxf(b2f(y[e]) * bn[e].x + bn[e].y, 0.f));
                *(u16x8*)&dst[(row + lrow) * 64 + lchunk * 8] = o;
            }
        } else {
            // k >= 256 region of GATHER gemm: A from F1T, stride 128
            const u16* src = A2 + (size_t)j0 * 128 + (k0s - 256);
#pragma unroll
            for (int qq = 0; qq < 4; ++qq) {
                int row = rbase + qq * 8;   // wave-uniform LDS base; HW adds lane*16B
                async_cp16(&dst[row * 64], src + (size_t)(row + lrow) * 128 + lchunk * 8);
            }
        }
    };

    constexpr int NI = KT / 64;
    stageA(0, 0);
    __syncthreads();
#pragma unroll
    for (int i = 0; i < NI; ++i) {
        int k0 = i * 64;
        // B fragments for this iter straight from L2 (independent of barriers)
        bf16x8 breg[2][4];
#pragma unroll
        for (int ks = 0; ks < 2; ++ks)
#pragma unroll
            for (int jj = 0; jj < 4; ++jj)
                breg[ks][jj] = *(const bf16x8*)&Bg[(size_t)(wm + jj * 16 + l15) * KT +
                                                   k0 + ks * 32 + q * 8];
        if (i + 1 < NI) stageA(k0 + 64, (i + 1) & 1);   // overlaps compute below
        const u16* buf = Al + (i & 1) * 8192;
#pragma unroll
        for (int ks = 0; ks < 2; ++ks) {
            bf16x8 af[4];
#pragma unroll
            for (int ii = 0; ii < 4; ++ii)
                af[ii] = *(const bf16x8*)&buf[(wj + ii * 16 + l15) * 64 + ks * 32 + q * 8];
#pragma unroll
            for (int ii = 0; ii < 4; ++ii)
#pragma unroll
                for (int jj = 0; jj < 4; ++jj)
                    acc[ii][jj] = __builtin_amdgcn_mfma_f32_16x16x32_bf16(af[ii], breg[ks][jj],
                                                                          acc[ii][jj], 0, 0, 0);
        }
        __syncthreads();   // separates {stage(i+1), compute(i)} || {stage(i+2), compute(i+1)}
    }
    // epilogue: stats + bf16 tile into LDS (D col = lane&15 -> m, row = q*4+reg -> j)
#pragma unroll
    for (int jj = 0; jj < 4; ++jj) {
        int ml = wm + jj * 16 + l15;
        float bv = bias[m0 + ml];
        float s = 0.f, s2 = 0.f;
#pragma unroll
        for (int i = 0; i < 4; ++i) {
            int jl = wj + i * 16 + q * 4;
#pragma unroll
            for (int r = 0; r < 4; ++r) {
                float v = acc[i][jj][r] + bv;
                s += v; s2 += v * v;
                T[(jl + r) * 136 + ml] = f2b(v);
            }
        }
        s += __shfl_xor(s, 16); s += __shfl_xor(s, 32);
        s2 += __shfl_xor(s2, 16); s2 += __shfl_xor(s2, 32);
        if (q == 0) {
            atomicAdd(&stats[m0 + ml], s);
            atomicAdd(&stats[256 + m0 + ml], s2);
        }
    }
    __syncthreads();
    // coalesced store: each wave covers 4 rows x 128 ch per iter (256 B segments)
#pragma unroll
    for (int it = 0; it < 8; ++it) {
        int jl = it * 16 + wv * 4 + q;
        u16x8 v = *(const u16x8*)&T[jl * 136 + l15 * 8];
        *(u16x8*)&Yb[(size_t)(j0 + jl) * 256 + m0 + l15 * 8] = v;
    }
}

// ---------- BN2+ReLU (inline finalize) + transpose [j][o] -> out[b][o][n] ----------
__global__ __launch_bounds__(256) void final_out_kernel(const u16* __restrict__ Y2,
                                                        const float* __restrict__ stats,
                                                        const float* __restrict__ g,
                                                        const float* __restrict__ be,
                                                        float* __restrict__ out) {
    __shared__ float t[64][65];
    int j0 = blockIdx.x * 64, o0 = blockIdx.y * 64;
    int tid = threadIdx.x;
    int c4 = (tid & 15) * 4, rw = tid >> 4;
#pragma unroll
    for (int p = 0; p < 4; ++p) {
        int jl = p * 16 + rw;
        ushort4 v = *(const ushort4*)&Y2[(size_t)(j0 + jl) * 256 + o0 + c4];
        t[jl][c4] = b2f(v.x); t[jl][c4 + 1] = b2f(v.y);
        t[jl][c4 + 2] = b2f(v.z); t[jl][c4 + 3] = b2f(v.w);
    }
    __syncthreads();
    int b = j0 >> 13, n0 = j0 & 8191;
    const float inv = 1.f / 32768.f;
#pragma unroll
    for (int p = 0; p < 4; ++p) {
        int ol = p * 16 + rw;
        int o = o0 + ol;
        float mean = stats[o] * inv;
        float var = stats[256 + o] * inv - mean * mean;
        float a = g[o] * rsqrtf(var + 1e-5f);
        float s = be[o] - mean * a;
        float4 v;
        v.x = fmaxf(t[c4][ol] * a + s, 0.f);
        v.y = fmaxf(t[c4 + 1][ol] * a + s, 0.f);
        v.z = fmaxf(t[c4 + 2][ol] * a + s, 0.f);
        v.w = fmaxf(t[c4 + 3][ol] * a + s, 0.f);
        *(float4*)&out[(size_t)b * 2097152 + (size_t)o * 8192 + n0 + c4] = v;
    }
}

extern "C" void kernel_launch(void* const* d_in, const int* in_sizes, int n_in,
                              void* d_out, int out_size, void* d_ws, size_t ws_size,
                              hipStream_t stream) {
    const float* pos1 = (const float*)d_in[0];
    const float* pos2 = (const float*)d_in[1];
    const float* feature1 = (const float*)d_in[2];
    const float* feature2 = (const float*)d_in[3];
    const float* W1 = (const float*)d_in[4];
    const float* b1 = (const float*)d_in[5];
    const float* g1 = (const float*)d_in[6];
    const float* be1 = (const float*)d_in[7];
    const float* W2 = (const float*)d_in[8];
    const float* b2 = (const float*)d_in[9];
    const float* g2 = (const float*)d_in[10];
    const float* be2 = (const float*)d_in[11];

    char* ws = (char*)d_ws;
    int*   IDX    = (int*)(ws + 0);                 // 393216 B
    float* WGT    = (float*)(ws + 393216);          // 393216 B
    u16*   W1B    = (u16*)(ws + 786432);            // 196608 B
    u16*   W2B    = (u16*)(ws + 983040);            // 131072 B (contiguous after W1B)
    float* STATS  = (float*)(ws + 1114112);         // 4096 B: sum1/sq1/sum2/sq2
    u16*   F2T    = (u16*)(ws + 1118208);           // 4 MiB  [4][2048][256]
    u16*   F1T    = (u16*)(ws + 5312512);           // 8 MiB  [4][8192][128]
    u16*   Y1     = (u16*)(ws + 13701120);          // 16 MiB [32768][256]
    u16*   Y2     = (u16*)(ws + 30478336);          // 16 MiB
    float* OUT    = (float*)d_out;

    hipMemsetAsync(STATS, 0, 1024 * sizeof(float), stream);
    prep_kernel<<<NB_NN + NB_CVT + NB_T2 + NB_T1, 256, 0, stream>>>(
        W1, W2, W1B, feature2, F2T, feature1, F1T, pos1, pos2, IDX, WGT);
    gemm_kernel<384, true, false><<<dim3(256, 2), 256, 0, stream>>>(
        F2T, F1T, W1B, b1, IDX, WGT, nullptr, nullptr, nullptr, Y1, STATS);
    gemm_kernel<256, false, true><<<dim3(256, 2), 256, 0, stream>>>(
        Y1, nullptr, W2B, b2, nullptr, nullptr, STATS, g1, be1, Y2, STATS + 512);
    final_out_kernel<<<dim3(512, 4), 256, 0, stream>>>(Y2, STATS + 512, g2, be2, OUT);
}

// Round 12
// 199.537 us; speedup vs baseline: 1.1766x; 1.0408x over previous
//
#include <hip/hip_runtime.h>
#include <hip/hip_bf16.h>
#include <cstdint>

typedef unsigned short u16;
typedef unsigned int u32;
typedef unsigned long long u64;
typedef __bf16 bf16x8 __attribute__((ext_vector_type(8)));
typedef float f32x4 __attribute__((ext_vector_type(4)));
typedef u16 u16x8 __attribute__((ext_vector_type(8)));

// ---------- helpers ----------
__device__ __forceinline__ u16 f2b(float f) {          // fp32 -> bf16 RNE
    unsigned int u = __float_as_uint(f);
    u += 0x7fffu + ((u >> 16) & 1u);
    return (u16)(u >> 16);
}
__device__ __forceinline__ float b2f(u16 h) {
    return __uint_as_float(((unsigned int)h) << 16);
}
__device__ __forceinline__ void async_cp16(void* lds, const void* g) {
    __builtin_amdgcn_global_load_lds((const __attribute__((address_space(1))) void*)g,
                                     (__attribute__((address_space(3))) void*)lds, 16, 0, 0);
}
// monotone unsigned mapping of float bits (order-preserving, EXACT)
__device__ __forceinline__ u32 fmono(float f) {
    u32 u = __float_as_uint(f);
    return u ^ (((u32)((int)u >> 31)) | 0x80000000u);
}
__device__ __forceinline__ u64 shfl_xor_u64(u64 v, int mask) {
    u32 lo = (u32)v, hi = (u32)(v >> 32);
    lo = (u32)__shfl_xor((int)lo, mask);
    hi = (u32)__shfl_xor((int)hi, mask);
    return ((u64)hi << 32) | lo;
}
// insert exact key into descending top-3 (keys unique: idx field breaks ties)
__device__ __forceinline__ void ins3(u64 k, u64& k0, u64& k1, u64& k2) {
    bool c0 = k > k0, c1 = k > k1, c2 = k > k2;
    k2 = c1 ? k1 : (c2 ? k : k2);
    k1 = c0 ? k0 : (c1 ? k : k1);
    k0 = c0 ? k : k0;
}
// padded pk index: one float4 pad every 64 entries (chunk groups on distinct banks)
__device__ __forceinline__ int pkix(int i) { return i + (i >> 6); }

// ================= prep kernel: three_nn FIRST, then cvt + transposes =================
#define NB_NN  512
#define NB_CVT 160
#define NB_T2  512
#define NB_T1  1024

__global__ __launch_bounds__(256, 4) void prep_kernel(const float* __restrict__ w1,
                                                      const float* __restrict__ w2,
                                                      u16* __restrict__ wb,
                                                      const float* __restrict__ feature2,
                                                      u16* __restrict__ f2t,
                                                      const float* __restrict__ feature1,
                                                      u16* __restrict__ f1t,
                                                      const float* __restrict__ pos1,
                                                      const float* __restrict__ pos2,
                                                      int* __restrict__ idx_out,
                                                      float* __restrict__ w_out) {
    __shared__ __align__(16) char smem[22784];   // 16640 pk-half + 6144 warr
    int bi = blockIdx.x;
    int tid = threadIdx.x;

    if (bi >= NB_NN) {
        int ci = bi - NB_NN;
        if (ci < NB_CVT) {
            int i = ci * 256 + tid;
            if (i < 40960) {
                const float* src = (i < 24576) ? w1 : w2;
                int k = (i < 24576) ? i : (i - 24576);
                float4 v = *(const float4*)&src[(size_t)k * 4];
                ushort4 o;
                o.x = f2b(v.x); o.y = f2b(v.y); o.z = f2b(v.z); o.w = f2b(v.w);
                *(ushort4*)&wb[(size_t)i * 4] = o;
            }
            return;
        }
        // ---- transpose [B][C][S] -> [B][S][C] bf16 ----
        float (*t)[65] = (float (*)[65])smem;
        const float* in; u16* out; int C, S, s0, c0, b;
        if (ci < NB_CVT + NB_T2) {
            int lin = ci - NB_CVT;
            C = 256; S = 2048; in = feature2; out = f2t;
            s0 = (lin & 31) * 64; c0 = ((lin >> 5) & 3) * 64; b = lin >> 7;
        } else {
            int lin = ci - NB_CVT - NB_T2;
            C = 128; S = 8192; in = feature1; out = f1t;
            s0 = (lin & 127) * 64; c0 = ((lin >> 7) & 1) * 64; b = lin >> 8;
        }
        const float* ib = in + (size_t)b * C * S;
        u16* ob = out + (size_t)b * S * C;
        int col = tid & 63, r0 = tid >> 6;
#pragma unroll
        for (int p = 0; p < 16; ++p) {
            int c = p * 4 + r0;
            t[c][col] = ib[(size_t)(c0 + c) * S + s0 + col];
        }
        __syncthreads();
#pragma unroll
        for (int p = 0; p < 16; ++p) {
            int s = p * 4 + r0;
            ob[(size_t)(s0 + s) * C + c0 + col] = f2b(t[col][s]);
        }
        return;
    }

    // ---- three_nn: 64 queries/block; thread handles queries p, p+16, p+32, p+48 ----
    float4* pk = (float4*)smem;                          // padded: 1040 float4 = 16640 B
    u64* warr = (u64*)(smem + 16640);                    // [4 waves][16 p][4 q][3]
    int j0 = bi * 64;
    int b = j0 >> 13;
    const float* p2 = pos2 + (size_t)b * 3 * 2048;
    int p = tid & 15, ck = tid >> 4;
    int wv = tid >> 6, lane = tid & 63;
    const float* p1 = pos1 + (size_t)b * 3 * 8192;
    float qx[4], qy[4], qz[4];
#pragma unroll
    for (int t = 0; t < 4; ++t) {
        int n = (j0 & 8191) + p + t * 16;
        qx[t] = p1[n]; qy[t] = p1[8192 + n]; qz[t] = p1[16384 + n];
    }
    u64 key[4][3];
#pragma unroll
    for (int t = 0; t < 4; ++t) { key[t][0] = 0; key[t][1] = 0; key[t][2] = 0; }

    for (int half = 0; half < 2; ++half) {
        int hbase = half * 1024;
        for (int i = tid; i < 1024; i += 256) {
            int s = hbase + i;
            float x = p2[s], y = p2[2048 + s], z = p2[4096 + s];
            pk[pkix(i)] = make_float4(x, y, z, -0.5f * (x * x + y * y + z * z));
        }
        __syncthreads();

        float g[4][3]; int id[4][3];
#pragma unroll
        for (int t = 0; t < 4; ++t) {
            g[t][0] = -3.4e38f; g[t][1] = -3.4e38f; g[t][2] = -3.4e38f;
            id[t][0] = 0; id[t][1] = 0; id[t][2] = 0;
        }
        int sb = ck * 64;
        const float4* pc = pk + pkix(sb);
#pragma unroll 2
        for (int it = 0; it < 64; ++it) {
            float4 cd = pc[it];
            int s = sb + it;
#pragma unroll
            for (int t = 0; t < 4; ++t) {
                float tv = fmaf(qx[t], cd.x, fmaf(qy[t], cd.y, fmaf(qz[t], cd.z, cd.w)));
                bool c0 = tv > g[t][0], c1 = tv > g[t][1], c2 = tv > g[t][2];
                g[t][2] = c1 ? g[t][1] : (c2 ? tv : g[t][2]);
                id[t][2] = c1 ? id[t][1] : (c2 ? s : id[t][2]);
                g[t][1] = c0 ? g[t][0] : (c1 ? tv : g[t][1]);
                id[t][1] = c0 ? id[t][0] : (c1 ? s : id[t][1]);
                g[t][0] = c0 ? tv : g[t][0];
                id[t][0] = c0 ? s : id[t][0];
            }
        }
        __syncthreads();   // reads done before next half restages

#pragma unroll
        for (int t = 0; t < 4; ++t) {
#pragma unroll
            for (int r = 0; r < 3; ++r)
                ins3(((u64)fmono(g[t][r]) << 32) | (u64)(2047 - (hbase + id[t][r])),
                     key[t][0], key[t][1], key[t][2]);
        }
    }

    // in-wave merge across the 4 chunk-groups (lane>>4)
#pragma unroll
    for (int mask = 16; mask <= 32; mask <<= 1) {
#pragma unroll
        for (int t = 0; t < 4; ++t) {
            u64 m0 = shfl_xor_u64(key[t][0], mask);
            u64 m1 = shfl_xor_u64(key[t][1], mask);
            u64 m2 = shfl_xor_u64(key[t][2], mask);
            ins3(m0, key[t][0], key[t][1], key[t][2]);
            ins3(m1, key[t][0], key[t][1], key[t][2]);
            ins3(m2, key[t][0], key[t][1], key[t][2]);
        }
    }
    if (lane < 16) {
        u64* wr = &warr[(wv * 16 + p) * 12];
#pragma unroll
        for (int t = 0; t < 4; ++t) {
            wr[t * 3 + 0] = key[t][0]; wr[t * 3 + 1] = key[t][1]; wr[t * 3 + 2] = key[t][2];
        }
    }
    __syncthreads();
    if (tid < 64) {
        int pp = tid & 15, t = tid >> 4;
        const u64* w0 = &warr[pp * 12 + t * 3];
        u64 k0 = w0[0], k1 = w0[1], k2 = w0[2];
#pragma unroll
        for (int w = 1; w < 4; ++w) {
            const u64* wr = &warr[(w * 16 + pp) * 12 + t * 3];
            ins3(wr[0], k0, k1, k2);
            ins3(wr[1], k0, k1, k2);
            ins3(wr[2], k0, k1, k2);
        }
        int s0 = 2047 - (int)(k0 & 0xFFFFFFFFu);
        int s1 = 2047 - (int)(k1 & 0xFFFFFFFFu);
        int s2 = 2047 - (int)(k2 & 0xFFFFFFFFu);
        int j = j0 + pp + t * 16;
        int n = j & 8191;
        float x1 = p1[n], y1 = p1[8192 + n], z1 = p1[16384 + n];
        float n1 = x1 * x1 + y1 * y1 + z1 * z1;
        float X0 = p2[s0], Y0 = p2[2048 + s0], Z0 = p2[4096 + s0];
        float X1 = p2[s1], Y1v = p2[2048 + s1], Z1 = p2[4096 + s1];
        float X2 = p2[s2], Y2v = p2[2048 + s2], Z2 = p2[4096 + s2];
        float t0 = x1 * X0 + y1 * Y0 + z1 * Z0 - 0.5f * (X0 * X0 + Y0 * Y0 + Z0 * Z0);
        float t1 = x1 * X1 + y1 * Y1v + z1 * Z1 - 0.5f * (X1 * X1 + Y1v * Y1v + Z1 * Z1);
        float t2 = x1 * X2 + y1 * Y2v + z1 * Z2 - 0.5f * (X2 * X2 + Y2v * Y2v + Z2 * Z2);
        float d0 = fmaxf(fmaf(-2.f, t0, n1), 1e-10f);
        float d1 = fmaxf(fmaf(-2.f, t1, n1), 1e-10f);
        float d2 = fmaxf(fmaf(-2.f, t2, n1), 1e-10f);
        float w0v = 1.f / d0, w1v = 1.f / d1, w2v = 1.f / d2;
        float inv = 1.f / (w0v + w1v + w2v);
        idx_out[j * 3] = s0; idx_out[j * 3 + 1] = s1; idx_out[j * 3 + 2] = s2;
        w_out[j * 3] = w0v * inv; w_out[j * 3 + 1] = w1v * inv; w_out[j * 3 + 2] = w2v * inv;
    }
}

// ---------- GEMM: Yb[j][m] = bf16(sum_k A[j][k]*Bw[m][k] + bias[m]), fused BN stats ----------
// R9 structure (128x128 tile, grid 256x2, 2 barriers/iter) + XOR bank swizzle:
// LDS[row][p] holds logical k-chunk p ^ (row&7). Async staging swizzles the per-lane GLOBAL
// source chunk (dst is forced lane-contiguous); VALU staging swizzles the ds_write column;
// ds_reads use column (ks*4+q) ^ (l15&7). Kills the 16-way same-bank conflict of stride-128B rows.
template <int KT, bool GATHER, bool FUSE>
__global__ __launch_bounds__(256, 2) void gemm_kernel(const u16* __restrict__ A1,
                                                      const u16* __restrict__ A2,
                                                      const u16* __restrict__ Bw,
                                                      const float* __restrict__ bias,
                                                      const int* __restrict__ idx,
                                                      const float* __restrict__ wgt,
                                                      const float* __restrict__ stats_in,
                                                      const float* __restrict__ g_in,
                                                      const float* __restrict__ be_in,
                                                      u16* __restrict__ Yb,
                                                      float* __restrict__ stats) {
    __shared__ __align__(16) char smemA[36864];
    u16* Al = (u16*)smemA;                       // [128][64], k-loop (swizzled cols)
    u16* Bl = (u16*)(smemA + 16384);             // [128][64], k-loop (swizzled cols)
    u16* T  = (u16*)smemA;                       // [128][136] epilogue bounce (overlays Al/Bl)
    float2* BNT = (float2*)(smemA + 34816);      // 256 x (scale, shift), FUSE only
    int tid = threadIdx.x;
    int lane = tid & 63, wv = tid >> 6;
    int j0 = blockIdx.x * 128, m0 = blockIdx.y * 128;
    int l15 = lane & 15, q = lane >> 4;
    int wj = (wv >> 1) * 64, wm = (wv & 1) * 64;
    f32x4 acc[4][4];
#pragma unroll
    for (int i = 0; i < 4; ++i)
#pragma unroll
        for (int jj = 0; jj < 4; ++jj) acc[i][jj] = (f32x4){0.f, 0.f, 0.f, 0.f};

    int rbase = wv * 32;
    int lrow = lane >> 3, lchunk = lane & 7;
    int schunk = lchunk ^ lrow;                  // swizzled chunk for staging
    const u16* Bg = Bw + (size_t)m0 * KT;

    if (FUSE) {
        int m = tid;
        const float inv = 1.f / 32768.f;
        float mean = stats_in[m] * inv;
        float var = stats_in[256 + m] * inv - mean * mean;
        float a = g_in[m] * rsqrtf(var + 1e-5f);
        BNT[m] = make_float2(a, be_in[m] - mean * a);
        __syncthreads();
    }

    // GATHER: hoist this thread's 4 rows' idx/wgt + row base pointers into registers
    const u16* grow0[4]; const u16* grow1[4]; const u16* grow2[4];
    float gw0[4], gw1[4], gw2[4];
    if (GATHER) {
#pragma unroll
        for (int qq = 0; qq < 4; ++qq) {
            int jl = rbase + qq * 8 + lrow;
            int j = j0 + jl;
            int bb = j >> 13;
            const u16* fb = A1 + (size_t)bb * 2048 * 256;   // A1 = F2T
            grow0[qq] = fb + (size_t)idx[j * 3 + 0] * 256;
            grow1[qq] = fb + (size_t)idx[j * 3 + 1] * 256;
            grow2[qq] = fb + (size_t)idx[j * 3 + 2] * 256;
            gw0[qq] = wgt[j * 3 + 0]; gw1[qq] = wgt[j * 3 + 1]; gw2[qq] = wgt[j * 3 + 2];
        }
    }

    for (int k0 = 0; k0 < KT; k0 += 64) {
        // B staging: per-lane global source reads the SWIZZLED chunk so the forced
        // lane-contiguous LDS landing yields swizzled columns.
#pragma unroll
        for (int qq = 0; qq < 4; ++qq) {
            int row = rbase + qq * 8;
            async_cp16(&Bl[row * 64], Bg + (size_t)(row + lrow) * KT + k0 + schunk * 8);
        }
        if (GATHER && k0 < 256) {
            int c = k0 + lchunk * 8;   // logical source chunk
#pragma unroll
            for (int qq = 0; qq < 4; ++qq) {
                int row = rbase + qq * 8;
                u16x8 v0 = *(const u16x8*)(grow0[qq] + c);
                u16x8 v1 = *(const u16x8*)(grow1[qq] + c);
                u16x8 v2 = *(const u16x8*)(grow2[qq] + c);
                u16x8 o;
#pragma unroll
                for (int e = 0; e < 8; ++e)
                    o[e] = f2b(gw0[qq] * b2f(v0[e]) + gw1[qq] * b2f(v1[e]) + gw2[qq] * b2f(v2[e]));
                *(u16x8*)&Al[(row + lrow) * 64 + schunk * 8] = o;   // swizzled ds_write col
            }
        } else if (FUSE) {
            int c = k0 + lchunk * 8;
            float2 bn[8];
#pragma unroll
            for (int e = 0; e < 8; ++e) bn[e] = BNT[c + e];
#pragma unroll
            for (int qq = 0; qq < 4; ++qq) {
                int row = rbase + qq * 8;
                u16x8 y = *(const u16x8*)&A1[(size_t)(j0 + row + lrow) * 256 + c];
                u16x8 o;
#pragma unroll
                for (int e = 0; e < 8; ++e)
                    o[e] = f2b(fmaxf(b2f(y[e]) * bn[e].x + bn[e].y, 0.f));
                *(u16x8*)&Al[(row + lrow) * 64 + schunk * 8] = o;   // swizzled ds_write col
            }
        } else {
            // k >= 256 region of GATHER gemm: A from F1T, stride 128 (swizzled source chunk)
            const u16* src = A2 + (size_t)j0 * 128 + (k0 - 256);
#pragma unroll
            for (int qq = 0; qq < 4; ++qq) {
                int row = rbase + qq * 8;
                async_cp16(&Al[row * 64], src + (size_t)(row + lrow) * 128 + schunk * 8);
            }
        }
        __syncthreads();
#pragma unroll
        for (int ks = 0; ks < 2; ++ks) {
            bf16x8 af[4], bfr[4];
#pragma unroll
            for (int i = 0; i < 4; ++i) {
                int row = wj + i * 16 + l15;
                af[i] = *(const bf16x8*)&Al[row * 64 + ((ks * 4 + q) ^ (l15 & 7)) * 8];
            }
#pragma unroll
            for (int i = 0; i < 4; ++i) {
                int row = wm + i * 16 + l15;
                bfr[i] = *(const bf16x8*)&Bl[row * 64 + ((ks * 4 + q) ^ (l15 & 7)) * 8];
            }
#pragma unroll
            for (int i = 0; i < 4; ++i)
#pragma unroll
                for (int jj = 0; jj < 4; ++jj)
                    acc[i][jj] = __builtin_amdgcn_mfma_f32_16x16x32_bf16(af[i], bfr[jj],
                                                                         acc[i][jj], 0, 0, 0);
        }
        __syncthreads();
    }
    // epilogue: stats + bf16 tile into LDS (D col = lane&15 -> m, row = q*4+reg -> j)
#pragma unroll
    for (int jj = 0; jj < 4; ++jj) {
        int ml = wm + jj * 16 + l15;
        float bv = bias[m0 + ml];
        float s = 0.f, s2 = 0.f;
#pragma unroll
        for (int i = 0; i < 4; ++i) {
            int jl = wj + i * 16 + q * 4;
#pragma unroll
            for (int r = 0; r < 4; ++r) {
                float v = acc[i][jj][r] + bv;
                s += v; s2 += v * v;
                T[(jl + r) * 136 + ml] = f2b(v);
            }
        }
        s += __shfl_xor(s, 16); s += __shfl_xor(s, 32);
        s2 += __shfl_xor(s2, 16); s2 += __shfl_xor(s2, 32);
        if (q == 0) {
            atomicAdd(&stats[m0 + ml], s);
            atomicAdd(&stats[256 + m0 + ml], s2);
        }
    }
    __syncthreads();
    // coalesced store: each wave covers 4 rows x 128 ch per iter (256 B segments)
#pragma unroll
    for (int it = 0; it < 8; ++it) {
        int jl = it * 16 + wv * 4 + q;
        u16x8 v = *(const u16x8*)&T[jl * 136 + l15 * 8];
        *(u16x8*)&Yb[(size_t)(j0 + jl) * 256 + m0 + l15 * 8] = v;
    }
}

// ---------- BN2+ReLU (inline finalize) + transpose [j][o] -> out[b][o][n] ----------
__global__ __launch_bounds__(256) void final_out_kernel(const u16* __restrict__ Y2,
                                                        const float* __restrict__ stats,
                                                        const float* __restrict__ g,
                                                        const float* __restrict__ be,
                                                        float* __restrict__ out) {
    __shared__ float t[64][65];
    int j0 = blockIdx.x * 64, o0 = blockIdx.y * 64;
    int tid = threadIdx.x;
    int c4 = (tid & 15) * 4, rw = tid >> 4;
#pragma unroll
    for (int p = 0; p < 4; ++p) {
        int jl = p * 16 + rw;
        ushort4 v = *(const ushort4*)&Y2[(size_t)(j0 + jl) * 256 + o0 + c4];
        t[jl][c4] = b2f(v.x); t[jl][c4 + 1] = b2f(v.y);
        t[jl][c4 + 2] = b2f(v.z); t[jl][c4 + 3] = b2f(v.w);
    }
    __syncthreads();
    int b = j0 >> 13, n0 = j0 & 8191;
    const float inv = 1.f / 32768.f;
#pragma unroll
    for (int p = 0; p < 4; ++p) {
        int ol = p * 16 + rw;
        int o = o0 + ol;
        float mean = stats[o] * inv;
        float var = stats[256 + o] * inv - mean * mean;
        float a = g[o] * rsqrtf(var + 1e-5f);
        float s = be[o] - mean * a;
        float4 v;
        v.x = fmaxf(t[c4][ol] * a + s, 0.f);
        v.y = fmaxf(t[c4 + 1][ol] * a + s, 0.f);
        v.z = fmaxf(t[c4 + 2][ol] * a + s, 0.f);
        v.w = fmaxf(t[c4 + 3][ol] * a + s, 0.f);
        *(float4*)&out[(size_t)b * 2097152 + (size_t)o * 8192 + n0 + c4] = v;
    }
}

extern "C" void kernel_launch(void* const* d_in, const int* in_sizes, int n_in,
                              void* d_out, int out_size, void* d_ws, size_t ws_size,
                              hipStream_t stream) {
    const float* pos1 = (const float*)d_in[0];
    const float* pos2 = (const float*)d_in[1];
    const float* feature1 = (const float*)d_in[2];
    const float* feature2 = (const float*)d_in[3];
    const float* W1 = (const float*)d_in[4];
    const float* b1 = (const float*)d_in[5];
    const float* g1 = (const float*)d_in[6];
    const float* be1 = (const float*)d_in[7];
    const float* W2 = (const float*)d_in[8];
    const float* b2 = (const float*)d_in[9];
    const float* g2 = (const float*)d_in[10];
    const float* be2 = (const float*)d_in[11];

    char* ws = (char*)d_ws;
    int*   IDX    = (int*)(ws + 0);                 // 393216 B
    float* WGT    = (float*)(ws + 393216);          // 393216 B
    u16*   W1B    = (u16*)(ws + 786432);            // 196608 B
    u16*   W2B    = (u16*)(ws + 983040);            // 131072 B (contiguous after W1B)
    float* STATS  = (float*)(ws + 1114112);         // 4096 B: sum1/sq1/sum2/sq2
    u16*   F2T    = (u16*)(ws + 1118208);           // 4 MiB  [4][2048][256]
    u16*   F1T    = (u16*)(ws + 5312512);           // 8 MiB  [4][8192][128]
    u16*   Y1     = (u16*)(ws + 13701120);          // 16 MiB [32768][256]
    u16*   Y2     = (u16*)(ws + 30478336);          // 16 MiB
    float* OUT    = (float*)d_out;

    hipMemsetAsync(STATS, 0, 1024 * sizeof(float), stream);
    prep_kernel<<<NB_NN + NB_CVT + NB_T2 + NB_T1, 256, 0, stream>>>(
        W1, W2, W1B, feature2, F2T, feature1, F1T, pos1, pos2, IDX, WGT);
    gemm_kernel<384, true, false><<<dim3(256, 2), 256, 0, stream>>>(
        F2T, F1T, W1B, b1, IDX, WGT, nullptr, nullptr, nullptr, Y1, STATS);
    gemm_kernel<256, false, true><<<dim3(256, 2), 256, 0, stream>>>(
        Y1, nullptr, W2B, b2, nullptr, nullptr, STATS, g1, be1, Y2, STATS + 512);
    final_out_kernel<<<dim3(512, 4), 256, 0, stream>>>(Y2, STATS + 512, g2, be2, OUT);
}

// Round 13
// 188.633 us; speedup vs baseline: 1.2446x; 1.0578x over previous
//
#include <hip/hip_runtime.h>
#include <hip/hip_bf16.h>
#include <cstdint>

typedef unsigned short u16;
typedef unsigned int u32;
typedef unsigned long long u64;
typedef __bf16 bf16x8 __attribute__((ext_vector_type(8)));
typedef float f32x4 __attribute__((ext_vector_type(4)));
typedef u16 u16x8 __attribute__((ext_vector_type(8)));

// ---------- helpers ----------
__device__ __forceinline__ u16 f2b(float f) {          // fp32 -> bf16 RNE
    unsigned int u = __float_as_uint(f);
    u += 0x7fffu + ((u >> 16) & 1u);
    return (u16)(u >> 16);
}
__device__ __forceinline__ float b2f(u16 h) {
    return __uint_as_float(((unsigned int)h) << 16);
}
__device__ __forceinline__ void async_cp16(void* lds, const void* g) {
    __builtin_amdgcn_global_load_lds((const __attribute__((address_space(1))) void*)g,
                                     (__attribute__((address_space(3))) void*)lds, 16, 0, 0);
}
// monotone unsigned mapping of float bits (order-preserving, EXACT)
__device__ __forceinline__ u32 fmono(float f) {
    u32 u = __float_as_uint(f);
    return u ^ (((u32)((int)u >> 31)) | 0x80000000u);
}
__device__ __forceinline__ u64 shfl_xor_u64(u64 v, int mask) {
    u32 lo = (u32)v, hi = (u32)(v >> 32);
    lo = (u32)__shfl_xor((int)lo, mask);
    hi = (u32)__shfl_xor((int)hi, mask);
    return ((u64)hi << 32) | lo;
}
// insert exact key into descending top-3 (keys unique: idx field breaks ties)
__device__ __forceinline__ void ins3(u64 k, u64& k0, u64& k1, u64& k2) {
    bool c0 = k > k0, c1 = k > k1, c2 = k > k2;
    k2 = c1 ? k1 : (c2 ? k : k2);
    k1 = c0 ? k0 : (c1 ? k : k1);
    k0 = c0 ? k : k0;
}
// padded pk index: one float4 pad every 64 entries (chunk groups on distinct banks)
__device__ __forceinline__ int pkix(int i) { return i + (i >> 6); }

// ================= prep kernel: three_nn FIRST, then cvt + transposes =================
#define NB_NN  512
#define NB_CVT 160
#define NB_T2  512
#define NB_T1  1024

__global__ __launch_bounds__(256, 4) void prep_kernel(const float* __restrict__ w1,
                                                      const float* __restrict__ w2,
                                                      u16* __restrict__ wb,
                                                      const float* __restrict__ feature2,
                                                      u16* __restrict__ f2t,
                                                      const float* __restrict__ feature1,
                                                      u16* __restrict__ f1t,
                                                      const float* __restrict__ pos1,
                                                      const float* __restrict__ pos2,
                                                      int* __restrict__ idx_out,
                                                      float* __restrict__ w_out) {
    __shared__ __align__(16) char smem[22784];   // 16640 pk-half + 6144 warr
    int bi = blockIdx.x;
    int tid = threadIdx.x;

    if (bi >= NB_NN) {
        int ci = bi - NB_NN;
        if (ci < NB_CVT) {
            int i = ci * 256 + tid;
            if (i < 40960) {
                const float* src = (i < 24576) ? w1 : w2;
                int k = (i < 24576) ? i : (i - 24576);
                float4 v = *(const float4*)&src[(size_t)k * 4];
                ushort4 o;
                o.x = f2b(v.x); o.y = f2b(v.y); o.z = f2b(v.z); o.w = f2b(v.w);
                *(ushort4*)&wb[(size_t)i * 4] = o;
            }
            return;
        }
        // ---- transpose [B][C][S] -> [B][S][C] bf16 ----
        float (*t)[65] = (float (*)[65])smem;
        const float* in; u16* out; int C, S, s0, c0, b;
        if (ci < NB_CVT + NB_T2) {
            int lin = ci - NB_CVT;
            C = 256; S = 2048; in = feature2; out = f2t;
            s0 = (lin & 31) * 64; c0 = ((lin >> 5) & 3) * 64; b = lin >> 7;
        } else {
            int lin = ci - NB_CVT - NB_T2;
            C = 128; S = 8192; in = feature1; out = f1t;
            s0 = (lin & 127) * 64; c0 = ((lin >> 7) & 1) * 64; b = lin >> 8;
        }
        const float* ib = in + (size_t)b * C * S;
        u16* ob = out + (size_t)b * S * C;
        int col = tid & 63, r0 = tid >> 6;
#pragma unroll
        for (int p = 0; p < 16; ++p) {
            int c = p * 4 + r0;
            t[c][col] = ib[(size_t)(c0 + c) * S + s0 + col];
        }
        __syncthreads();
#pragma unroll
        for (int p = 0; p < 16; ++p) {
            int s = p * 4 + r0;
            ob[(size_t)(s0 + s) * C + c0 + col] = f2b(t[col][s]);
        }
        return;
    }

    // ---- three_nn: 64 queries/block; thread handles queries p, p+16, p+32, p+48 ----
    float4* pk = (float4*)smem;                          // padded: 1040 float4 = 16640 B
    u64* warr = (u64*)(smem + 16640);                    // [4 waves][16 p][4 q][3]
    int j0 = bi * 64;
    int b = j0 >> 13;
    const float* p2 = pos2 + (size_t)b * 3 * 2048;
    int p = tid & 15, ck = tid >> 4;
    int wv = tid >> 6, lane = tid & 63;
    const float* p1 = pos1 + (size_t)b * 3 * 8192;
    float qx[4], qy[4], qz[4];
#pragma unroll
    for (int t = 0; t < 4; ++t) {
        int n = (j0 & 8191) + p + t * 16;
        qx[t] = p1[n]; qy[t] = p1[8192 + n]; qz[t] = p1[16384 + n];
    }
    u64 key[4][3];
#pragma unroll
    for (int t = 0; t < 4; ++t) { key[t][0] = 0; key[t][1] = 0; key[t][2] = 0; }

    for (int half = 0; half < 2; ++half) {
        int hbase = half * 1024;
        for (int i = tid; i < 1024; i += 256) {
            int s = hbase + i;
            float x = p2[s], y = p2[2048 + s], z = p2[4096 + s];
            pk[pkix(i)] = make_float4(x, y, z, -0.5f * (x * x + y * y + z * z));
        }
        __syncthreads();

        float g[4][3]; int id[4][3];
#pragma unroll
        for (int t = 0; t < 4; ++t) {
            g[t][0] = -3.4e38f; g[t][1] = -3.4e38f; g[t][2] = -3.4e38f;
            id[t][0] = 0; id[t][1] = 0; id[t][2] = 0;
        }
        int sb = ck * 64;
        const float4* pc = pk + pkix(sb);
#pragma unroll 2
        for (int it = 0; it < 64; ++it) {
            float4 cd = pc[it];
            int s = sb + it;
#pragma unroll
            for (int t = 0; t < 4; ++t) {
                float tv = fmaf(qx[t], cd.x, fmaf(qy[t], cd.y, fmaf(qz[t], cd.z, cd.w)));
                bool c0 = tv > g[t][0], c1 = tv > g[t][1], c2 = tv > g[t][2];
                g[t][2] = c1 ? g[t][1] : (c2 ? tv : g[t][2]);
                id[t][2] = c1 ? id[t][1] : (c2 ? s : id[t][2]);
                g[t][1] = c0 ? g[t][0] : (c1 ? tv : g[t][1]);
                id[t][1] = c0 ? id[t][0] : (c1 ? s : id[t][1]);
                g[t][0] = c0 ? tv : g[t][0];
                id[t][0] = c0 ? s : id[t][0];
            }
        }
        __syncthreads();   // reads done before next half restages

#pragma unroll
        for (int t = 0; t < 4; ++t) {
#pragma unroll
            for (int r = 0; r < 3; ++r)
                ins3(((u64)fmono(g[t][r]) << 32) | (u64)(2047 - (hbase + id[t][r])),
                     key[t][0], key[t][1], key[t][2]);
        }
    }

    // in-wave merge across the 4 chunk-groups (lane>>4)
#pragma unroll
    for (int mask = 16; mask <= 32; mask <<= 1) {
#pragma unroll
        for (int t = 0; t < 4; ++t) {
            u64 m0 = shfl_xor_u64(key[t][0], mask);
            u64 m1 = shfl_xor_u64(key[t][1], mask);
            u64 m2 = shfl_xor_u64(key[t][2], mask);
            ins3(m0, key[t][0], key[t][1], key[t][2]);
            ins3(m1, key[t][0], key[t][1], key[t][2]);
            ins3(m2, key[t][0], key[t][1], key[t][2]);
        }
    }
    if (lane < 16) {
        u64* wr = &warr[(wv * 16 + p) * 12];
#pragma unroll
        for (int t = 0; t < 4; ++t) {
            wr[t * 3 + 0] = key[t][0]; wr[t * 3 + 1] = key[t][1]; wr[t * 3 + 2] = key[t][2];
        }
    }
    __syncthreads();
    if (tid < 64) {
        int pp = tid & 15, t = tid >> 4;
        const u64* w0 = &warr[pp * 12 + t * 3];
        u64 k0 = w0[0], k1 = w0[1], k2 = w0[2];
#pragma unroll
        for (int w = 1; w < 4; ++w) {
            const u64* wr = &warr[(w * 16 + pp) * 12 + t * 3];
            ins3(wr[0], k0, k1, k2);
            ins3(wr[1], k0, k1, k2);
            ins3(wr[2], k0, k1, k2);
        }
        int s0 = 2047 - (int)(k0 & 0xFFFFFFFFu);
        int s1 = 2047 - (int)(k1 & 0xFFFFFFFFu);
        int s2 = 2047 - (int)(k2 & 0xFFFFFFFFu);
        int j = j0 + pp + t * 16;
        int n = j & 8191;
        float x1 = p1[n], y1 = p1[8192 + n], z1 = p1[16384 + n];
        float n1 = x1 * x1 + y1 * y1 + z1 * z1;
        float X0 = p2[s0], Y0 = p2[2048 + s0], Z0 = p2[4096 + s0];
        float X1 = p2[s1], Y1v = p2[2048 + s1], Z1 = p2[4096 + s1];
        float X2 = p2[s2], Y2v = p2[2048 + s2], Z2 = p2[4096 + s2];
        float t0 = x1 * X0 + y1 * Y0 + z1 * Z0 - 0.5f * (X0 * X0 + Y0 * Y0 + Z0 * Z0);
        float t1 = x1 * X1 + y1 * Y1v + z1 * Z1 - 0.5f * (X1 * X1 + Y1v * Y1v + Z1 * Z1);
        float t2 = x1 * X2 + y1 * Y2v + z1 * Z2 - 0.5f * (X2 * X2 + Y2v * Y2v + Z2 * Z2);
        float d0 = fmaxf(fmaf(-2.f, t0, n1), 1e-10f);
        float d1 = fmaxf(fmaf(-2.f, t1, n1), 1e-10f);
        float d2 = fmaxf(fmaf(-2.f, t2, n1), 1e-10f);
        float w0v = 1.f / d0, w1v = 1.f / d1, w2v = 1.f / d2;
        float inv = 1.f / (w0v + w1v + w2v);
        idx_out[j * 3] = s0; idx_out[j * 3 + 1] = s1; idx_out[j * 3 + 2] = s2;
        w_out[j * 3] = w0v * inv; w_out[j * 3 + 1] = w1v * inv; w_out[j * 3 + 2] = w2v * inv;
    }
}

// ---------- GEMM: Yb[j][m] = bf16(sum_k A[j][k]*Bw[m][k] + bias[m]) ----------
// R12 structure (128x128 tile, swizzled LDS). BN stats: NO ATOMICS — each block-half
// writes its per-channel partial sum/sumsq to P[512][512] (each slot written once).
// GATHER: k<256 A = interp gather from F2T; k>=256 A from F1T (async).
// FUSE:   A = relu(bn1(Y1)) using precomputed (scale,shift) table bnt_in.
template <int KT, bool GATHER, bool FUSE>
__global__ __launch_bounds__(256, 2) void gemm_kernel(const u16* __restrict__ A1,
                                                      const u16* __restrict__ A2,
                                                      const u16* __restrict__ Bw,
                                                      const float* __restrict__ bias,
                                                      const int* __restrict__ idx,
                                                      const float* __restrict__ wgt,
                                                      const float2* __restrict__ bnt_in,
                                                      u16* __restrict__ Yb,
                                                      float* __restrict__ Pt) {
    __shared__ __align__(16) char smemA[36864];
    u16* Al = (u16*)smemA;                       // [128][64], k-loop (swizzled cols)
    u16* Bl = (u16*)(smemA + 16384);             // [128][64], k-loop (swizzled cols)
    u16* T  = (u16*)smemA;                       // [128][136] epilogue bounce (overlays Al/Bl)
    float2* BNT = (float2*)(smemA + 34816);      // 256 x (scale, shift), FUSE only
    int tid = threadIdx.x;
    int lane = tid & 63, wv = tid >> 6;
    int j0 = blockIdx.x * 128, m0 = blockIdx.y * 128;
    int l15 = lane & 15, q = lane >> 4;
    int wj = (wv >> 1) * 64, wm = (wv & 1) * 64;
    f32x4 acc[4][4];
#pragma unroll
    for (int i = 0; i < 4; ++i)
#pragma unroll
        for (int jj = 0; jj < 4; ++jj) acc[i][jj] = (f32x4){0.f, 0.f, 0.f, 0.f};

    int rbase = wv * 32;
    int lrow = lane >> 3, lchunk = lane & 7;
    int schunk = lchunk ^ lrow;                  // swizzled chunk for staging
    const u16* Bg = Bw + (size_t)m0 * KT;

    if (FUSE) {
        BNT[tid] = bnt_in[tid];                  // precomputed fold: (scale, shift)
        __syncthreads();
    }

    // GATHER: hoist this thread's 4 rows' idx/wgt + row base pointers into registers
    const u16* grow0[4]; const u16* grow1[4]; const u16* grow2[4];
    float gw0[4], gw1[4], gw2[4];
    if (GATHER) {
#pragma unroll
        for (int qq = 0; qq < 4; ++qq) {
            int jl = rbase + qq * 8 + lrow;
            int j = j0 + jl;
            int bb = j >> 13;
            const u16* fb = A1 + (size_t)bb * 2048 * 256;   // A1 = F2T
            grow0[qq] = fb + (size_t)idx[j * 3 + 0] * 256;
            grow1[qq] = fb + (size_t)idx[j * 3 + 1] * 256;
            grow2[qq] = fb + (size_t)idx[j * 3 + 2] * 256;
            gw0[qq] = wgt[j * 3 + 0]; gw1[qq] = wgt[j * 3 + 1]; gw2[qq] = wgt[j * 3 + 2];
        }
    }

    for (int k0 = 0; k0 < KT; k0 += 64) {
        // B staging: per-lane global source reads the SWIZZLED chunk so the forced
        // lane-contiguous LDS landing yields swizzled columns.
#pragma unroll
        for (int qq = 0; qq < 4; ++qq) {
            int row = rbase + qq * 8;
            async_cp16(&Bl[row * 64], Bg + (size_t)(row + lrow) * KT + k0 + schunk * 8);
        }
        if (GATHER && k0 < 256) {
            int c = k0 + lchunk * 8;   // logical source chunk
#pragma unroll
            for (int qq = 0; qq < 4; ++qq) {
                int row = rbase + qq * 8;
                u16x8 v0 = *(const u16x8*)(grow0[qq] + c);
                u16x8 v1 = *(const u16x8*)(grow1[qq] + c);
                u16x8 v2 = *(const u16x8*)(grow2[qq] + c);
                u16x8 o;
#pragma unroll
                for (int e = 0; e < 8; ++e)
                    o[e] = f2b(gw0[qq] * b2f(v0[e]) + gw1[qq] * b2f(v1[e]) + gw2[qq] * b2f(v2[e]));
                *(u16x8*)&Al[(row + lrow) * 64 + schunk * 8] = o;   // swizzled ds_write col
            }
        } else if (FUSE) {
            int c = k0 + lchunk * 8;
            float2 bn[8];
#pragma unroll
            for (int e = 0; e < 8; ++e) bn[e] = BNT[c + e];
#pragma unroll
            for (int qq = 0; qq < 4; ++qq) {
                int row = rbase + qq * 8;
                u16x8 y = *(const u16x8*)&A1[(size_t)(j0 + row + lrow) * 256 + c];
                u16x8 o;
#pragma unroll
                for (int e = 0; e < 8; ++e)
                    o[e] = f2b(fmaxf(b2f(y[e]) * bn[e].x + bn[e].y, 0.f));
                *(u16x8*)&Al[(row + lrow) * 64 + schunk * 8] = o;   // swizzled ds_write col
            }
        } else {
            // k >= 256 region of GATHER gemm: A from F1T, stride 128 (swizzled source chunk)
            const u16* src = A2 + (size_t)j0 * 128 + (k0 - 256);
#pragma unroll
            for (int qq = 0; qq < 4; ++qq) {
                int row = rbase + qq * 8;
                async_cp16(&Al[row * 64], src + (size_t)(row + lrow) * 128 + schunk * 8);
            }
        }
        __syncthreads();
#pragma unroll
        for (int ks = 0; ks < 2; ++ks) {
            bf16x8 af[4], bfr[4];
#pragma unroll
            for (int i = 0; i < 4; ++i) {
                int row = wj + i * 16 + l15;
                af[i] = *(const bf16x8*)&Al[row * 64 + ((ks * 4 + q) ^ (l15 & 7)) * 8];
            }
#pragma unroll
            for (int i = 0; i < 4; ++i) {
                int row = wm + i * 16 + l15;
                bfr[i] = *(const bf16x8*)&Bl[row * 64 + ((ks * 4 + q) ^ (l15 & 7)) * 8];
            }
#pragma unroll
            for (int i = 0; i < 4; ++i)
#pragma unroll
                for (int jj = 0; jj < 4; ++jj)
                    acc[i][jj] = __builtin_amdgcn_mfma_f32_16x16x32_bf16(af[i], bfr[jj],
                                                                         acc[i][jj], 0, 0, 0);
        }
        __syncthreads();
    }
    // epilogue: per-channel partials + bf16 tile into LDS (D col -> m, row = q*4+reg -> j)
#pragma unroll
    for (int jj = 0; jj < 4; ++jj) {
        int ml = wm + jj * 16 + l15;
        float bv = bias[m0 + ml];
        float s = 0.f, s2 = 0.f;
#pragma unroll
        for (int i = 0; i < 4; ++i) {
            int jl = wj + i * 16 + q * 4;
#pragma unroll
            for (int r = 0; r < 4; ++r) {
                float v = acc[i][jj][r] + bv;
                s += v; s2 += v * v;
                T[(jl + r) * 136 + ml] = f2b(v);
            }
        }
        s += __shfl_xor(s, 16); s += __shfl_xor(s, 32);
        s2 += __shfl_xor(s2, 16); s2 += __shfl_xor(s2, 32);
        if (q == 0) {
            // NO atomics: partial row = blockIdx.x*2 + (wj half); each slot written once
            size_t prow = (size_t)blockIdx.x * 2 + (wv >> 1);
            Pt[prow * 512 + (m0 + ml)] = s;
            Pt[prow * 512 + 256 + (m0 + ml)] = s2;
        }
    }
    __syncthreads();
    // coalesced store: each wave covers 4 rows x 128 ch per iter (256 B segments)
#pragma unroll
    for (int it = 0; it < 8; ++it) {
        int jl = it * 16 + wv * 4 + q;
        u16x8 v = *(const u16x8*)&T[jl * 136 + l15 * 8];
        *(u16x8*)&Yb[(size_t)(j0 + jl) * 256 + m0 + l15 * 8] = v;
    }
}

// ---------- reduce partials -> folded BN (scale, shift) table ----------
// grid 4 x 256; block handles 64 channels; P is [512][512] (sum[0..255], sq[256..511])
__global__ __launch_bounds__(256) void reduce_kernel(const float* __restrict__ P,
                                                     const float* __restrict__ g,
                                                     const float* __restrict__ be,
                                                     float2* __restrict__ bnt) {
    __shared__ float ls[4][64], ls2[4][64];
    int tid = threadIdx.x;
    int ch = blockIdx.x * 64 + (tid & 63);
    int rg = tid >> 6;
    float s = 0.f, s2 = 0.f;
    for (int r = rg * 128; r < rg * 128 + 128; ++r) {
        s += P[(size_t)r * 512 + ch];
        s2 += P[(size_t)r * 512 + 256 + ch];
    }
    ls[rg][tid & 63] = s; ls2[rg][tid & 63] = s2;
    __syncthreads();
    if (tid < 64) {
        float fs = ls[0][tid] + ls[1][tid] + ls[2][tid] + ls[3][tid];
        float fs2 = ls2[0][tid] + ls2[1][tid] + ls2[2][tid] + ls2[3][tid];
        int c = blockIdx.x * 64 + tid;
        const float inv = 1.f / 32768.f;
        float mean = fs * inv;
        float var = fs2 * inv - mean * mean;
        float a = g[c] * rsqrtf(var + 1e-5f);
        bnt[c] = make_float2(a, be[c] - mean * a);
    }
}

// ---------- BN2+ReLU (precomputed table) + transpose [j][o] -> out[b][o][n] ----------
__global__ __launch_bounds__(256) void final_out_kernel(const u16* __restrict__ Y2,
                                                        const float2* __restrict__ bnt,
                                                        float* __restrict__ out) {
    __shared__ float t[64][65];
    int j0 = blockIdx.x * 64, o0 = blockIdx.y * 64;
    int tid = threadIdx.x;
    int c4 = (tid & 15) * 4, rw = tid >> 4;
#pragma unroll
    for (int p = 0; p < 4; ++p) {
        int jl = p * 16 + rw;
        ushort4 v = *(const ushort4*)&Y2[(size_t)(j0 + jl) * 256 + o0 + c4];
        t[jl][c4] = b2f(v.x); t[jl][c4 + 1] = b2f(v.y);
        t[jl][c4 + 2] = b2f(v.z); t[jl][c4 + 3] = b2f(v.w);
    }
    __syncthreads();
    int b = j0 >> 13, n0 = j0 & 8191;
#pragma unroll
    for (int p = 0; p < 4; ++p) {
        int ol = p * 16 + rw;
        int o = o0 + ol;
        float2 bn = bnt[o];
        float a = bn.x, s = bn.y;
        float4 v;
        v.x = fmaxf(t[c4][ol] * a + s, 0.f);
        v.y = fmaxf(t[c4 + 1][ol] * a + s, 0.f);
        v.z = fmaxf(t[c4 + 2][ol] * a + s, 0.f);
        v.w = fmaxf(t[c4 + 3][ol] * a + s, 0.f);
        *(float4*)&out[(size_t)b * 2097152 + (size_t)o * 8192 + n0 + c4] = v;
    }
}

extern "C" void kernel_launch(void* const* d_in, const int* in_sizes, int n_in,
                              void* d_out, int out_size, void* d_ws, size_t ws_size,
                              hipStream_t stream) {
    const float* pos1 = (const float*)d_in[0];
    const float* pos2 = (const float*)d_in[1];
    const float* feature1 = (const float*)d_in[2];
    const float* feature2 = (const float*)d_in[3];
    const float* W1 = (const float*)d_in[4];
    const float* b1 = (const float*)d_in[5];
    const float* g1 = (const float*)d_in[6];
    const float* be1 = (const float*)d_in[7];
    const float* W2 = (const float*)d_in[8];
    const float* b2 = (const float*)d_in[9];
    const float* g2 = (const float*)d_in[10];
    const float* be2 = (const float*)d_in[11];

    char* ws = (char*)d_ws;
    int*    IDX   = (int*)(ws + 0);                 // 393216 B
    float*  WGT   = (float*)(ws + 393216);          // 393216 B
    u16*    W1B   = (u16*)(ws + 786432);            // 196608 B
    u16*    W2B   = (u16*)(ws + 983040);            // 131072 B (contiguous after W1B)
    float2* BNT1G = (float2*)(ws + 1114112);        // 2048 B folded BN1 (scale, shift)
    float2* BNT2G = (float2*)(ws + 1116160);        // 2048 B folded BN2
    u16*    F2T   = (u16*)(ws + 1118208);           // 4 MiB  [4][2048][256]
    u16*    F1T   = (u16*)(ws + 5312512);           // 8 MiB  [4][8192][128]
    u16*    Y1    = (u16*)(ws + 13701120);          // 16 MiB [32768][256]
    u16*    Y2    = (u16*)(ws + 30478336);          // 16 MiB
    float*  P1    = (float*)(ws + 47255552);        // 1 MiB [512][512] partials gemm1
    float*  P2    = (float*)(ws + 48304128);        // 1 MiB partials gemm2
    float*  OUT   = (float*)d_out;

    prep_kernel<<<NB_NN + NB_CVT + NB_T2 + NB_T1, 256, 0, stream>>>(
        W1, W2, W1B, feature2, F2T, feature1, F1T, pos1, pos2, IDX, WGT);
    gemm_kernel<384, true, false><<<dim3(256, 2), 256, 0, stream>>>(
        F2T, F1T, W1B, b1, IDX, WGT, nullptr, Y1, P1);
    reduce_kernel<<<4, 256, 0, stream>>>(P1, g1, be1, BNT1G);
    gemm_kernel<256, false, true><<<dim3(256, 2), 256, 0, stream>>>(
        Y1, nullptr, W2B, b2, nullptr, nullptr, BNT1G, Y2, P2);
    reduce_kernel<<<4, 256, 0, stream>>>(P2, g2, be2, BNT2G);
    final_out_kernel<<<dim3(512, 4), 256, 0, stream>>>(Y2, BNT2G, OUT);
}